// Round 5
// baseline (307.031 us; speedup 1.0000x reference)
//
#include <hip/hip_runtime.h>
#include <stdint.h>

// BoltzmannGateSTE: out = x * (|x| >= T), T = k-th largest |x|, k = int(n/e).
// R5 structure (5 dispatches + 1 memset; NO cooperative sync):
//   memset (~4.8 MB: state + fineH + fallback hists)
//   pass_partition -- R5: nontemporal loads + 2-stage software pipeline +
//     __launch_bounds__(256,4) (128 VGPRs; the old (256,8) capped at 64 and
//     starved the loop). Semantics identical: stream x -> out with bracket
//     [LO,HI)=[0.88,0.92): u>=HI keep+count chi; u<LO zero; else candidate ->
//     placeholder 0, ballot-compacted append to per-wave arena buffer +
//     fire-and-forget atomicAdd into exact table fineH[u-LO] (671K entries).
//   kcs: 656 blocks coarse-sum fineH + 64 blocks pack (chi,tot) partials;
//     last-block ticket -> winner verifies chi < k <= chi+tot, coarse+fine
//     descending wave-shuffle scans -> exact threshold bits in state[S_T].
//   post1: flag==0 -> wavecnt-guided fixup (valid arena prefixes, ~5.6MB);
//          flag!=0 -> fallback hist1 (4096 bins) + last-block select1.
//   post2: gated fallback hist2 (2^19 fine bins) + last-block select2.
//   post3: gated fallback mask pass.
// MEASURED LESSONS ENCODED HERE:
//   R1/R3: cg::grid.sync() costs ~114 us EACH on MI355X under graph capture
//     (R3 epilogue: 2 syncs = 228 us; R1: 3 syncs explained 392 us). NEVER
//     use cooperative kernels here; plain dispatch boundaries cost ~0.8 us
//     (R4: removing 6 dispatches saved 4.9 us). Last-block ticket
//     (threadfence + atomicAdd) replaces cross-block sync for free.
//   R1: a nontemporal-load streaming phase ran at ~47 us ~= the 268 MB HBM
//     floor -> partition CAN hit floor; R5 applies the same ingredients.
//   R2: select scan barriers were only ~0.6 us. Harness re-poison fills
//     (~90-95 us each, 512 MiB) dominate the timed region and are untouchable.
// Exact gated fallback covers arbitrary inputs if the bracket or a wave buffer
// fails verification (deterministically never for this input; ~120 sigma).

constexpr unsigned LO_BITS = 0x3F6147AEu;        // bits(0.88f)
constexpr unsigned HI_BITS = 0x3F6B851Fu;        // bits(0.92f)
constexpr unsigned NKEY    = HI_BITS - LO_BITS;  // 671089 bracket bit patterns
constexpr int      NCB     = (NKEY + 1023) / 1024;   // 656 coarse bins

constexpr int P_GRID = 4096;                 // partition geometry
constexpr int P_BLK  = 256;
constexpr int P_WPB  = P_BLK / 64;           // 4 waves/block
constexpr int NWAVES = P_GRID * P_WPB;       // 16384
constexpr int CAPW   = 128;                  // slots/wave (mean ~43, 13 sigma)

constexpr int TPART  = 64;                   // tally partial blocks in kcs
constexpr int KCS_GRID = NCB + TPART;        // 720

constexpr int NBIN1   = 4096;                // fallback: bits[30:19]
constexpr int NFINE   = 1 << 19;
constexpr int NCOARSE = 512;

// state slots
#define S_PREF 0
#define S_K1   1
#define S_T    2
#define S_FLAG 3   // nonzero -> fallback chain active
#define S_TICK 4   // kcs last-block ticket
#define S_TICK2 5  // post1 fallback ticket
#define S_TICK3 6  // post2 fallback ticket

// ---------------- fast path: partition (R5: NT loads + pipeline) ----------
__global__ __launch_bounds__(P_BLK, 4)
void pass_partition(const uint4* __restrict__ x, long long n4,
                    uint4* __restrict__ out, uint2* __restrict__ cand,
                    unsigned* __restrict__ wavecnt, unsigned* __restrict__ blkchi,
                    unsigned* __restrict__ fineH, unsigned* __restrict__ state)
{
    typedef unsigned uv4 __attribute__((ext_vector_type(4)));
    const int lane  = threadIdx.x & 63;
    const int wid   = threadIdx.x >> 6;
    const int gwave = blockIdx.x * P_WPB + wid;
    uint2* my = cand + (size_t)gwave * CAPW;
    const unsigned long long lt = (1ull << lane) - 1ull;

    unsigned wcnt = 0;          // wave-uniform candidate count (lane0 exact)
    unsigned chi  = 0;          // per-thread >=HI tally
    const long long stride = (long long)gridDim.x * P_BLK;
    long long i = (long long)blockIdx.x * P_BLK + threadIdx.x;

    if (i < n4) {
        uint4 v;
        *(uv4*)&v = __builtin_nontemporal_load((const uv4*)(x + i));
        while (true) {
            const long long inext = i + stride;
            const bool has_next = (inext < n4);
            uint4 vn;
            if (has_next)
                *(uv4*)&vn = __builtin_nontemporal_load((const uv4*)(x + inext));

            uint4 r;
            unsigned idx0 = (unsigned)(i << 2);
#define DO_COMP(c, off)                                                        \
            { unsigned b = v.c, u = b & 0x7FFFFFFFu;                           \
              bool kp = (u >= HI_BITS);                                        \
              bool cd = (u >= LO_BITS) & !kp;                                  \
              chi += (unsigned)kp;                                             \
              r.c = kp ? b : 0u;                                               \
              unsigned long long m = __ballot(cd);                             \
              if (cd) {                                                        \
                  atomicAdd(&fineH[u - LO_BITS], 1u);  /* fire-and-forget */   \
                  unsigned pos = wcnt + (unsigned)__popcll(m & lt);            \
                  if (pos < (unsigned)CAPW) my[pos] = make_uint2(b, idx0 + off);\
              }                                                                \
              wcnt += (unsigned)__popcll(m); }
            DO_COMP(x, 0) DO_COMP(y, 1) DO_COMP(z, 2) DO_COMP(w, 3)
#undef DO_COMP
            __builtin_nontemporal_store(*(uv4*)&r, (uv4*)(out + i));
            if (!has_next) break;
            v = vn;
            i = inext;
        }
    }

    for (int m = 32; m; m >>= 1) chi += __shfl_xor(chi, m, 64);
    __shared__ unsigned s_chi[P_WPB];
    if (lane == 0) {
        s_chi[wid] = chi;
        wavecnt[gwave] = (wcnt < (unsigned)CAPW) ? wcnt : (unsigned)CAPW;
        if (wcnt > (unsigned)CAPW) atomicOr(&state[S_FLAG], 1u);
    }
    __syncthreads();
    if (threadIdx.x == 0) {
        unsigned a = 0;
        for (int w = 0; w < P_WPB; ++w) a += s_chi[w];
        blkchi[blockIdx.x] = a;
    }
}

// ---- descending single-chunk select over nbins<=1024 (1024-thread block) ----
__device__ __forceinline__ void select1k(const unsigned* __restrict__ hist, int nbins,
                                         unsigned k, unsigned* s_wsum, int* s_res)
{
    const int tid = threadIdx.x, lane = tid & 63, wid = tid >> 6;
    __syncthreads();                       // protect caller's s_res reads
    if (tid == 0) { s_res[0] = 0; s_res[1] = 1; }   // safe default
    int bin = nbins - 1 - tid;
    unsigned v = (bin >= 0) ? hist[bin] : 0u;
    unsigned p = v;
#pragma unroll
    for (int off = 1; off < 64; off <<= 1) {
        unsigned t = __shfl_up(p, off, 64);
        if (lane >= off) p += t;
    }
    if (lane == 63) s_wsum[wid] = p;
    __syncthreads();
    unsigned wpref = 0;
#pragma unroll
    for (int w = 0; w < 16; ++w) {
        unsigned ws = s_wsum[w];
        wpref += (w < wid) ? ws : 0u;
    }
    unsigned incl = wpref + p, excl = incl - v;
    if (bin >= 0 && incl >= k && excl < k) {   // exactly one thread (k<=total)
        s_res[0] = bin;
        s_res[1] = (int)(k - excl);
    }
    __syncthreads();
}

// ---- descending chunked select (TB-thread block, any nbins) ----
template<int TB>
__device__ void select_desc_t(const unsigned* __restrict__ hist, int nbins,
                              unsigned k, unsigned* s_wsum, int* s_res)
{
    constexpr int TW = TB / 64;
    const int tid  = threadIdx.x;
    const int lane = tid & 63;
    const int wid  = tid >> 6;
    __syncthreads();
    if (tid == 0) { s_res[0] = -1; s_res[1] = 0; }
    __syncthreads();
    unsigned running = 0;
    for (int top = nbins; top > 0; top -= TB) {
        int bin = top - 1 - tid;
        unsigned v = (bin >= 0) ? hist[bin] : 0u;
        unsigned p = v;
#pragma unroll
        for (int off = 1; off < 64; off <<= 1) {
            unsigned t = __shfl_up(p, off, 64);
            if (lane >= off) p += t;
        }
        if (lane == 63) s_wsum[wid] = p;
        __syncthreads();
        unsigned wpref = 0, total = 0;
#pragma unroll
        for (int w = 0; w < TW; ++w) {
            unsigned ws = s_wsum[w];
            wpref += (w < wid) ? ws : 0u;
            total += ws;
        }
        unsigned incl = wpref + p;
        unsigned excl = incl - v;
        if (running + total >= k) {     // block-uniform
            if (bin >= 0 && running + incl >= k && running + excl < k) {
                s_res[0] = bin;
                s_res[1] = (int)(k - running - excl);
            }
            __syncthreads();
            return;
        }
        running += total;
        __syncthreads();
    }
    __syncthreads();
}

// ---- kcs: coarse sums + tally partials + last-block verify/select ----
__global__ __launch_bounds__(1024)
void kcs(const unsigned* __restrict__ fineH,
         const unsigned* __restrict__ blkchi, const unsigned* __restrict__ wavecnt,
         unsigned* __restrict__ coarseH, unsigned long long* __restrict__ tpart,
         unsigned* __restrict__ state, unsigned k)
{
    __shared__ unsigned s_t[16];
    __shared__ unsigned s_wsum[16];
    __shared__ int s_res[2];
    __shared__ unsigned s_ct[2];
    __shared__ unsigned s_done;

    const int tid = threadIdx.x, lane = tid & 63, wid = tid >> 6;
    const int bid = blockIdx.x;

    if (bid < NCB) {
        unsigned key = ((unsigned)bid << 10) + (unsigned)tid;
        unsigned s = (key < NKEY) ? fineH[key] : 0u;
        for (int m = 32; m; m >>= 1) s += __shfl_xor(s, m, 64);
        if (lane == 0) s_t[wid] = s;
        __syncthreads();
        if (tid == 0) {
            unsigned a = 0;
#pragma unroll
            for (int w = 0; w < 16; ++w) a += s_t[w];
            coarseH[bid] = a;
        }
    } else {
        int b = bid - NCB;                                   // 0..63
        unsigned chi = (tid < 64)  ? blkchi[(b << 6) + tid]  : 0u;  // 4096=64*64
        unsigned tot = (tid < 256) ? wavecnt[(b << 8) + tid] : 0u;  // 16384=64*256
        for (int m = 32; m; m >>= 1) {
            chi += __shfl_xor(chi, m, 64);
            tot += __shfl_xor(tot, m, 64);
        }
        if (lane == 0) s_t[wid] = tot;
        __syncthreads();
        if (tid == 0) {                                      // tid0 = lane0 wave0
            unsigned tt = 0;
#pragma unroll
            for (int w = 0; w < 16; ++w) tt += s_t[w];
            tpart[b] = ((unsigned long long)chi << 32) | (unsigned long long)tt;
        }
    }
    __syncthreads();

    // last-block ticket: release writes, grab ticket; winner proceeds
    if (tid == 0) { __threadfence(); s_done = atomicAdd(&state[S_TICK], 1u); }
    __syncthreads();
    if (s_done != (unsigned)(KCS_GRID - 1)) return;
    __threadfence();                                          // acquire

    unsigned long long chiS = 0, totS = 0;
    if (wid == 0) {
        unsigned long long e = tpart[lane];                   // TPART == 64
        chiS = e >> 32; totS = e & 0xFFFFFFFFull;
        for (int m = 32; m; m >>= 1) {
            chiS += __shfl_xor(chiS, m, 64);
            totS += __shfl_xor(totS, m, 64);
        }
    }
    if (tid == 0) {
        unsigned fl = state[S_FLAG];
        if (fl == 0u && (chiS >= (unsigned long long)k ||
                         chiS + totS < (unsigned long long)k)) {
            atomicOr(&state[S_FLAG], 1u);    // bracket failed -> fallback
            fl = 1u;
        }
        s_ct[0] = (fl == 0u) ? 1u : 0u;
        s_ct[1] = (unsigned)((unsigned long long)k - chiS);
    }
    __syncthreads();
    if (!s_ct[0]) return;
    unsigned kp = s_ct[1];

    select1k(coarseH, NCB, kp, s_wsum, s_res);
    int cb = s_res[0];
    unsigned r = (unsigned)s_res[1];
    int nfine = (int)NKEY - (cb << 10);
    if (nfine > 1024) nfine = 1024;
    select1k(fineH + ((size_t)cb << 10), nfine, r, s_wsum, s_res);
    if (tid == 0)
        state[S_T] = LO_BITS + (unsigned)((cb << 10) + s_res[0]);
}

// ---- post1: fast fixup OR fallback hist1+select1 ----
__global__ __launch_bounds__(256, 8)
void post1(const uint4* __restrict__ x, long long n4, long long n,
           float* __restrict__ outF,
           const uint2* __restrict__ cand, const unsigned* __restrict__ wavecnt,
           unsigned* __restrict__ histA, unsigned* __restrict__ state, unsigned k)
{
    const int tid = threadIdx.x, lane = tid & 63, wid = tid >> 6;

    if (state[S_FLAG] == 0u) {
        // wavecnt-guided fixup: read only valid prefixes (~5.6 MB not 16.8 MB)
        unsigned T = state[S_T];
        int gw = blockIdx.x * 4 + wid;
        int gstride = (int)gridDim.x * 4;
        for (int w = gw; w < NWAVES; w += gstride) {
            unsigned cnt = wavecnt[w];
            const uint2* my = cand + (size_t)w * CAPW;
            for (unsigned j = (unsigned)lane; j < cnt; j += 64) {
                uint2 e = my[j];
                if ((e.x & 0x7FFFFFFFu) >= T && (long long)e.y < n)
                    outF[e.y] = __uint_as_float(e.x);
            }
        }
        return;
    }

    // ---- fallback: 4096-bin histogram of bits[30:19] ----
    __shared__ unsigned h[NBIN1];
    for (int i = tid; i < NBIN1; i += 256) h[i] = 0u;
    __syncthreads();
    long long stride = (long long)gridDim.x * 256;
    for (long long i = (long long)blockIdx.x * 256 + tid; i < n4; i += stride) {
        uint4 v = x[i];
        atomicAdd(&h[(v.x & 0x7FFFFFFFu) >> 19], 1u);
        atomicAdd(&h[(v.y & 0x7FFFFFFFu) >> 19], 1u);
        atomicAdd(&h[(v.z & 0x7FFFFFFFu) >> 19], 1u);
        atomicAdd(&h[(v.w & 0x7FFFFFFFu) >> 19], 1u);
    }
    __syncthreads();
    for (int i = tid; i < NBIN1; i += 256)
        if (h[i]) atomicAdd(&histA[i], h[i]);
    __syncthreads();

    __shared__ unsigned s_done;
    if (tid == 0) { __threadfence(); s_done = atomicAdd(&state[S_TICK2], 1u); }
    __syncthreads();
    if (s_done != gridDim.x - 1) return;
    __threadfence();

    __shared__ unsigned s_wsum[4];
    __shared__ int s_res[2];
    select_desc_t<256>(histA, NBIN1, k, s_wsum, s_res);
    if (tid == 0) {
        state[S_PREF] = (s_res[0] < 0) ? 0u : (unsigned)s_res[0];
        state[S_K1]   = (s_res[0] < 0) ? 1u : (unsigned)s_res[1];
    }
}

// ---- post2: gated fallback hist2+select2 ----
__global__ __launch_bounds__(256, 8)
void post2(const uint4* __restrict__ x, long long n4,
           unsigned* __restrict__ fineB, unsigned* __restrict__ coarseB,
           unsigned* __restrict__ state)
{
    if (state[S_FLAG] == 0u) return;
    const int tid = threadIdx.x;
    unsigned pref = state[S_PREF];

    __shared__ unsigned hc[NCOARSE];
    for (int i = tid; i < NCOARSE; i += 256) hc[i] = 0u;
    __syncthreads();
    long long stride = (long long)gridDim.x * 256;
    for (long long i = (long long)blockIdx.x * 256 + tid; i < n4; i += stride) {
        uint4 v = x[i];
        unsigned u;
#define DO_C(c) u = v.c & 0x7FFFFFFFu;                                        \
        if ((u >> 19) == pref) {                                              \
            atomicAdd(&fineB[u & (NFINE - 1)], 1u);                           \
            atomicAdd(&hc[(u & (NFINE - 1)) >> 10], 1u); }
        DO_C(x) DO_C(y) DO_C(z) DO_C(w)
#undef DO_C
    }
    __syncthreads();
    for (int i = tid; i < NCOARSE; i += 256)
        if (hc[i]) atomicAdd(&coarseB[i], hc[i]);
    __syncthreads();

    __shared__ unsigned s_done;
    if (tid == 0) { __threadfence(); s_done = atomicAdd(&state[S_TICK3], 1u); }
    __syncthreads();
    if (s_done != gridDim.x - 1) return;
    __threadfence();

    __shared__ unsigned s_wsum[4];
    __shared__ int s_res[2];
    unsigned k1 = state[S_K1];
    select_desc_t<256>(coarseB, NCOARSE, k1, s_wsum, s_res);
    int c       = (s_res[0] < 0) ? 0 : s_res[0];
    unsigned k2 = (s_res[0] < 0) ? 1u : (unsigned)s_res[1];
    __syncthreads();
    select_desc_t<256>(fineB + (size_t)c * 1024, 1024, k2, s_wsum, s_res);
    int f = (s_res[0] < 0) ? 0 : s_res[0];
    if (tid == 0)
        state[S_T] = (pref << 19) | ((unsigned)c << 10) | (unsigned)f;
}

// ---- post3: gated fallback mask pass ----
__global__ __launch_bounds__(256)
void post3(const uint4* __restrict__ x, uint4* __restrict__ out, long long n4,
           const unsigned* __restrict__ state)
{
    if (state[S_FLAG] == 0u) return;
    unsigned t = state[S_T];
    long long stride = (long long)gridDim.x * 256;
    for (long long i = (long long)blockIdx.x * 256 + threadIdx.x; i < n4; i += stride) {
        uint4 v = x[i];
        uint4 r;
        r.x = ((v.x & 0x7FFFFFFFu) >= t) ? v.x : 0u;
        r.y = ((v.y & 0x7FFFFFFFu) >= t) ? v.y : 0u;
        r.z = ((v.z & 0x7FFFFFFFu) >= t) ? v.z : 0u;
        r.w = ((v.w & 0x7FFFFFFFu) >= t) ? v.w : 0u;
        out[i] = r;
    }
}

__global__ void seed_flag(unsigned* state)
{
    if (threadIdx.x == 0) state[S_FLAG] = 1u;
}

// ---------------- host ----------------
extern "C" void kernel_launch(void* const* d_in, const int* in_sizes, int n_in,
                              void* d_out, int out_size, void* d_ws, size_t ws_size,
                              hipStream_t stream)
{
    long long n = (long long)in_sizes[0];
    if (n <= 0) return;
    long long n4 = n >> 2;   // n = 4*4096*2048, divisible by 4

    const double FRACTION = 1.0 / 2.718281828459045;   // matches Python 1.0/math.e
    long long k = (long long)((double)n * FRACTION);
    if (k < 1) k = 1;

    auto al = [](size_t v) { return (v + 63) & ~(size_t)63; };

    // zeroed region: state | fineH | fineB | coarseB | histA  (~4.8 MB)
    const size_t off_fineH   = 64;
    const size_t off_fineB   = al(off_fineH + (size_t)NKEY * 4);
    const size_t off_coarseB = off_fineB   + (size_t)NFINE * 4;    // contiguous
    const size_t off_histA   = off_coarseB + (size_t)NCOARSE * 4;  // contiguous
    const size_t zero_end    = off_histA   + (size_t)NBIN1 * 4;
    // non-zeroed region (fully overwritten each iteration)
    const size_t off_coarseH = al(zero_end);
    const size_t off_tpart   = al(off_coarseH + (size_t)NCB * 4);
    const size_t off_wcnt    = al(off_tpart + (size_t)TPART * 8);
    const size_t off_bchi    = al(off_wcnt + (size_t)NWAVES * 4);
    const size_t off_cand    = al(off_bchi + (size_t)P_GRID * 4);
    const size_t need_fast   = off_cand + (size_t)NWAVES * CAPW * 8;   // ~26 MB
    const size_t need_fb     = zero_end;

    const uint4* x = (const uint4*)d_in[0];

    if (ws_size >= need_fast) {
        uint8_t* base = (uint8_t*)d_ws;
        unsigned* state   = (unsigned*)base;
        unsigned* fineH   = (unsigned*)(base + off_fineH);
        unsigned* fineB   = (unsigned*)(base + off_fineB);
        unsigned* coarseB = (unsigned*)(base + off_coarseB);
        unsigned* histA   = (unsigned*)(base + off_histA);
        unsigned* coarseH = (unsigned*)(base + off_coarseH);
        unsigned long long* tpart = (unsigned long long*)(base + off_tpart);
        unsigned* wavecnt = (unsigned*)(base + off_wcnt);
        unsigned* blkchi  = (unsigned*)(base + off_bchi);
        uint2*    cand    = (uint2*)   (base + off_cand);

        hipMemsetAsync(base, 0, zero_end, stream);
        pass_partition<<<P_GRID, P_BLK, 0, stream>>>(x, n4, (uint4*)d_out, cand,
                                                     wavecnt, blkchi, fineH, state);
        kcs  <<<KCS_GRID, 1024, 0, stream>>>(fineH, blkchi, wavecnt, coarseH,
                                             tpart, state, (unsigned)k);
        post1<<<1024, 256, 0, stream>>>(x, n4, n, (float*)d_out, cand, wavecnt,
                                        histA, state, (unsigned)k);
        post2<<<256, 256, 0, stream>>>(x, n4, fineB, coarseB, state);
        post3<<<1024, 256, 0, stream>>>(x, (uint4*)d_out, n4, state);
    } else {
        // tiny workspace: run the exact fallback chain unconditionally
        uint8_t* base;
        unsigned* state = (unsigned*)d_ws;       // 64 B state always in d_ws
        bool in_ws = (ws_size >= need_fb);
        base = in_ws ? (uint8_t*)d_ws : (uint8_t*)d_out;  // stage hists in d_out
        unsigned* fineB   = (unsigned*)(base + off_fineB);
        unsigned* coarseB = (unsigned*)(base + off_coarseB);
        unsigned* histA   = (unsigned*)(base + off_histA);

        if (in_ws) {
            hipMemsetAsync(base, 0, zero_end, stream);
        } else {
            hipMemsetAsync(state, 0, 64, stream);
            hipMemsetAsync(base + off_fineB, 0,
                           ((size_t)NFINE + NCOARSE + NBIN1) * 4, stream);
        }
        seed_flag<<<1, 64, 0, stream>>>(state);
        post1<<<1024, 256, 0, stream>>>(x, n4, n, (float*)d_out,
                                        (const uint2*)base, (const unsigned*)base,
                                        histA, state, (unsigned)k);
        post2<<<256, 256, 0, stream>>>(x, n4, fineB, coarseB, state);
        post3<<<1024, 256, 0, stream>>>(x, (uint4*)d_out, n4, state);
    }
}

// Round 6
// 296.943 us; speedup vs baseline: 1.0340x; 1.0340x over previous
//
#include <hip/hip_runtime.h>
#include <stdint.h>

// BoltzmannGateSTE: out = x * (|x| >= T), T = k-th largest |x|, k = int(n/e).
// R6 == R4 (measured best: 299.6 us). R5's NT-load+pipeline+(256,4) partition
// REVERTED: it regressed to 307.0 us (halved occupancy for VGPRs the loop
// didn't need; TLP > ILP for streaming loops at full occupancy).
// Structure (5 dispatches + 1 memset; NO cooperative sync):
//   memset (~4.8 MB: state + fineH + fallback hists)
//   pass_partition -- proven BW-bound streaming loop, (256,8), unroll 2:
//     stream x -> out with bracket [LO,HI)=[0.88,0.92): u>=HI keep+count chi;
//     u<LO zero; else candidate -> placeholder 0, ballot-compacted append to a
//     per-wave arena buffer + fire-and-forget atomicAdd into exact per-bit-
//     pattern table fineH[u-LO] (671K entries, ~1 hit/bin).
//   kcs: 656 blocks coarse-sum fineH + 64 blocks pack (chi,tot) partials;
//     last-block ticket (threadfence+atomicAdd) -> winner verifies
//     chi < k <= chi+tot, coarse+fine descending wave-shuffle scans ->
//     exact threshold bits in state[S_T].
//   post1: flag==0 -> wavecnt-guided fixup (valid arena prefixes, ~5.6MB);
//          flag!=0 -> fallback hist1 (4096 bins) + last-block select1.
//   post2: gated fallback hist2 (2^19 fine bins) + last-block select2.
//   post3: gated fallback mask pass.
// MEASURED LESSONS:
//   R1/R3: cg::grid.sync() ~114 us EACH under graph capture -> never use
//     cooperative kernels here; dispatch boundaries cost ~0.8 us (R4).
//   R5: NT loads + ILP pipeline + (256,4) regressed (-7 us): occupancy rules.
//   R2: select barriers ~0.6 us. Harness re-poison fills (~95 us x2 + ~97 us
//     output copy per iter) dominate the timed region and are untouchable.
// Budget: ours ~80 us (partition ~65 vs 43 us floor, fixup ~8, rest ~8);
// harness ~220 us. Exact gated fallback covers arbitrary inputs if bracket or
// wave buffer fails verification (deterministically never here; ~120 sigma).

constexpr unsigned LO_BITS = 0x3F6147AEu;        // bits(0.88f)
constexpr unsigned HI_BITS = 0x3F6B851Fu;        // bits(0.92f)
constexpr unsigned NKEY    = HI_BITS - LO_BITS;  // 671089 bracket bit patterns
constexpr int      NCB     = (NKEY + 1023) / 1024;   // 656 coarse bins

constexpr int P_GRID = 4096;                 // partition geometry
constexpr int P_BLK  = 256;
constexpr int P_WPB  = P_BLK / 64;           // 4 waves/block
constexpr int NWAVES = P_GRID * P_WPB;       // 16384
constexpr int CAPW   = 128;                  // slots/wave (mean ~43, 13 sigma)

constexpr int TPART  = 64;                   // tally partial blocks in kcs
constexpr int KCS_GRID = NCB + TPART;        // 720

constexpr int NBIN1   = 4096;                // fallback: bits[30:19]
constexpr int NFINE   = 1 << 19;
constexpr int NCOARSE = 512;

// state slots
#define S_PREF 0
#define S_K1   1
#define S_T    2
#define S_FLAG 3   // nonzero -> fallback chain active
#define S_TICK 4   // kcs last-block ticket
#define S_TICK2 5  // post1 fallback ticket
#define S_TICK3 6  // post2 fallback ticket

// ---------------- fast path: partition (R4 version, proven best) ----------
__global__ __launch_bounds__(P_BLK, 8)
void pass_partition(const uint4* __restrict__ x, long long n4,
                    uint4* __restrict__ out, uint2* __restrict__ cand,
                    unsigned* __restrict__ wavecnt, unsigned* __restrict__ blkchi,
                    unsigned* __restrict__ fineH, unsigned* __restrict__ state)
{
    typedef unsigned uv4 __attribute__((ext_vector_type(4)));
    const int lane  = threadIdx.x & 63;
    const int wid   = threadIdx.x >> 6;
    const int gwave = blockIdx.x * P_WPB + wid;
    uint2* my = cand + (size_t)gwave * CAPW;
    const unsigned long long lt = (1ull << lane) - 1ull;

    unsigned wcnt = 0;          // wave-uniform candidate count
    unsigned chi  = 0;          // per-thread >=HI tally
    const long long stride = (long long)gridDim.x * P_BLK;
#pragma unroll 2
    for (long long i = (long long)blockIdx.x * P_BLK + threadIdx.x; i < n4; i += stride) {
        uint4 v = x[i];
        uint4 r;
        unsigned idx0 = (unsigned)(i << 2);
#define DO_COMP(c, off)                                                        \
        { unsigned b = v.c, u = b & 0x7FFFFFFFu;                               \
          bool kp = (u >= HI_BITS);                                            \
          bool cd = (u >= LO_BITS) & !kp;                                      \
          chi += (unsigned)kp;                                                 \
          r.c = kp ? b : 0u;                                                   \
          unsigned long long m = __ballot(cd);                                 \
          if (cd) {                                                            \
              atomicAdd(&fineH[u - LO_BITS], 1u);  /* fire-and-forget */       \
              unsigned pos = wcnt + (unsigned)__popcll(m & lt);                \
              if (pos < (unsigned)CAPW) my[pos] = make_uint2(b, idx0 + off);   \
          }                                                                    \
          wcnt += (unsigned)__popcll(m); }
        DO_COMP(x, 0) DO_COMP(y, 1) DO_COMP(z, 2) DO_COMP(w, 3)
#undef DO_COMP
        __builtin_nontemporal_store(*(uv4*)&r, (uv4*)(out + i));
    }

    for (int m = 32; m; m >>= 1) chi += __shfl_xor(chi, m, 64);
    __shared__ unsigned s_chi[P_WPB];
    if (lane == 0) {
        s_chi[wid] = chi;
        wavecnt[gwave] = (wcnt < (unsigned)CAPW) ? wcnt : (unsigned)CAPW;
        if (wcnt > (unsigned)CAPW) atomicOr(&state[S_FLAG], 1u);
    }
    __syncthreads();
    if (threadIdx.x == 0) {
        unsigned a = 0;
        for (int w = 0; w < P_WPB; ++w) a += s_chi[w];
        blkchi[blockIdx.x] = a;
    }
}

// ---- descending single-chunk select over nbins<=1024 (1024-thread block) ----
__device__ __forceinline__ void select1k(const unsigned* __restrict__ hist, int nbins,
                                         unsigned k, unsigned* s_wsum, int* s_res)
{
    const int tid = threadIdx.x, lane = tid & 63, wid = tid >> 6;
    __syncthreads();                       // protect caller's s_res reads
    if (tid == 0) { s_res[0] = 0; s_res[1] = 1; }   // safe default
    int bin = nbins - 1 - tid;
    unsigned v = (bin >= 0) ? hist[bin] : 0u;
    unsigned p = v;
#pragma unroll
    for (int off = 1; off < 64; off <<= 1) {
        unsigned t = __shfl_up(p, off, 64);
        if (lane >= off) p += t;
    }
    if (lane == 63) s_wsum[wid] = p;
    __syncthreads();
    unsigned wpref = 0;
#pragma unroll
    for (int w = 0; w < 16; ++w) {
        unsigned ws = s_wsum[w];
        wpref += (w < wid) ? ws : 0u;
    }
    unsigned incl = wpref + p, excl = incl - v;
    if (bin >= 0 && incl >= k && excl < k) {   // exactly one thread (k<=total)
        s_res[0] = bin;
        s_res[1] = (int)(k - excl);
    }
    __syncthreads();
}

// ---- descending chunked select (TB-thread block, any nbins) ----
template<int TB>
__device__ void select_desc_t(const unsigned* __restrict__ hist, int nbins,
                              unsigned k, unsigned* s_wsum, int* s_res)
{
    constexpr int TW = TB / 64;
    const int tid  = threadIdx.x;
    const int lane = tid & 63;
    const int wid  = tid >> 6;
    __syncthreads();
    if (tid == 0) { s_res[0] = -1; s_res[1] = 0; }
    __syncthreads();
    unsigned running = 0;
    for (int top = nbins; top > 0; top -= TB) {
        int bin = top - 1 - tid;
        unsigned v = (bin >= 0) ? hist[bin] : 0u;
        unsigned p = v;
#pragma unroll
        for (int off = 1; off < 64; off <<= 1) {
            unsigned t = __shfl_up(p, off, 64);
            if (lane >= off) p += t;
        }
        if (lane == 63) s_wsum[wid] = p;
        __syncthreads();
        unsigned wpref = 0, total = 0;
#pragma unroll
        for (int w = 0; w < TW; ++w) {
            unsigned ws = s_wsum[w];
            wpref += (w < wid) ? ws : 0u;
            total += ws;
        }
        unsigned incl = wpref + p;
        unsigned excl = incl - v;
        if (running + total >= k) {     // block-uniform
            if (bin >= 0 && running + incl >= k && running + excl < k) {
                s_res[0] = bin;
                s_res[1] = (int)(k - running - excl);
            }
            __syncthreads();
            return;
        }
        running += total;
        __syncthreads();
    }
    __syncthreads();
}

// ---- kcs: coarse sums + tally partials + last-block verify/select ----
__global__ __launch_bounds__(1024)
void kcs(const unsigned* __restrict__ fineH,
         const unsigned* __restrict__ blkchi, const unsigned* __restrict__ wavecnt,
         unsigned* __restrict__ coarseH, unsigned long long* __restrict__ tpart,
         unsigned* __restrict__ state, unsigned k)
{
    __shared__ unsigned s_t[16];
    __shared__ unsigned s_wsum[16];
    __shared__ int s_res[2];
    __shared__ unsigned s_ct[2];
    __shared__ unsigned s_done;

    const int tid = threadIdx.x, lane = tid & 63, wid = tid >> 6;
    const int bid = blockIdx.x;

    if (bid < NCB) {
        unsigned key = ((unsigned)bid << 10) + (unsigned)tid;
        unsigned s = (key < NKEY) ? fineH[key] : 0u;
        for (int m = 32; m; m >>= 1) s += __shfl_xor(s, m, 64);
        if (lane == 0) s_t[wid] = s;
        __syncthreads();
        if (tid == 0) {
            unsigned a = 0;
#pragma unroll
            for (int w = 0; w < 16; ++w) a += s_t[w];
            coarseH[bid] = a;
        }
    } else {
        int b = bid - NCB;                                   // 0..63
        unsigned chi = (tid < 64)  ? blkchi[(b << 6) + tid]  : 0u;  // 4096=64*64
        unsigned tot = (tid < 256) ? wavecnt[(b << 8) + tid] : 0u;  // 16384=64*256
        for (int m = 32; m; m >>= 1) {
            chi += __shfl_xor(chi, m, 64);
            tot += __shfl_xor(tot, m, 64);
        }
        if (lane == 0) s_t[wid] = tot;
        __syncthreads();
        if (tid == 0) {                                      // tid0 = lane0 wave0
            unsigned tt = 0;
#pragma unroll
            for (int w = 0; w < 16; ++w) tt += s_t[w];
            tpart[b] = ((unsigned long long)chi << 32) | (unsigned long long)tt;
        }
    }
    __syncthreads();

    // last-block ticket: release writes, grab ticket; winner proceeds
    if (tid == 0) { __threadfence(); s_done = atomicAdd(&state[S_TICK], 1u); }
    __syncthreads();
    if (s_done != (unsigned)(KCS_GRID - 1)) return;
    __threadfence();                                          // acquire

    unsigned long long chiS = 0, totS = 0;
    if (wid == 0) {
        unsigned long long e = tpart[lane];                   // TPART == 64
        chiS = e >> 32; totS = e & 0xFFFFFFFFull;
        for (int m = 32; m; m >>= 1) {
            chiS += __shfl_xor(chiS, m, 64);
            totS += __shfl_xor(totS, m, 64);
        }
    }
    if (tid == 0) {
        unsigned fl = state[S_FLAG];
        if (fl == 0u && (chiS >= (unsigned long long)k ||
                         chiS + totS < (unsigned long long)k)) {
            atomicOr(&state[S_FLAG], 1u);    // bracket failed -> fallback
            fl = 1u;
        }
        s_ct[0] = (fl == 0u) ? 1u : 0u;
        s_ct[1] = (unsigned)((unsigned long long)k - chiS);
    }
    __syncthreads();
    if (!s_ct[0]) return;
    unsigned kp = s_ct[1];

    select1k(coarseH, NCB, kp, s_wsum, s_res);
    int cb = s_res[0];
    unsigned r = (unsigned)s_res[1];
    int nfine = (int)NKEY - (cb << 10);
    if (nfine > 1024) nfine = 1024;
    select1k(fineH + ((size_t)cb << 10), nfine, r, s_wsum, s_res);
    if (tid == 0)
        state[S_T] = LO_BITS + (unsigned)((cb << 10) + s_res[0]);
}

// ---- post1: fast fixup OR fallback hist1+select1 ----
__global__ __launch_bounds__(256, 8)
void post1(const uint4* __restrict__ x, long long n4, long long n,
           float* __restrict__ outF,
           const uint2* __restrict__ cand, const unsigned* __restrict__ wavecnt,
           unsigned* __restrict__ histA, unsigned* __restrict__ state, unsigned k)
{
    const int tid = threadIdx.x, lane = tid & 63, wid = tid >> 6;

    if (state[S_FLAG] == 0u) {
        // wavecnt-guided fixup: read only valid prefixes (~5.6 MB not 16.8 MB)
        unsigned T = state[S_T];
        int gw = blockIdx.x * 4 + wid;
        int gstride = (int)gridDim.x * 4;
        for (int w = gw; w < NWAVES; w += gstride) {
            unsigned cnt = wavecnt[w];
            const uint2* my = cand + (size_t)w * CAPW;
            for (unsigned j = (unsigned)lane; j < cnt; j += 64) {
                uint2 e = my[j];
                if ((e.x & 0x7FFFFFFFu) >= T && (long long)e.y < n)
                    outF[e.y] = __uint_as_float(e.x);
            }
        }
        return;
    }

    // ---- fallback: 4096-bin histogram of bits[30:19] ----
    __shared__ unsigned h[NBIN1];
    for (int i = tid; i < NBIN1; i += 256) h[i] = 0u;
    __syncthreads();
    long long stride = (long long)gridDim.x * 256;
    for (long long i = (long long)blockIdx.x * 256 + tid; i < n4; i += stride) {
        uint4 v = x[i];
        atomicAdd(&h[(v.x & 0x7FFFFFFFu) >> 19], 1u);
        atomicAdd(&h[(v.y & 0x7FFFFFFFu) >> 19], 1u);
        atomicAdd(&h[(v.z & 0x7FFFFFFFu) >> 19], 1u);
        atomicAdd(&h[(v.w & 0x7FFFFFFFu) >> 19], 1u);
    }
    __syncthreads();
    for (int i = tid; i < NBIN1; i += 256)
        if (h[i]) atomicAdd(&histA[i], h[i]);
    __syncthreads();

    __shared__ unsigned s_done;
    if (tid == 0) { __threadfence(); s_done = atomicAdd(&state[S_TICK2], 1u); }
    __syncthreads();
    if (s_done != gridDim.x - 1) return;
    __threadfence();

    __shared__ unsigned s_wsum[4];
    __shared__ int s_res[2];
    select_desc_t<256>(histA, NBIN1, k, s_wsum, s_res);
    if (tid == 0) {
        state[S_PREF] = (s_res[0] < 0) ? 0u : (unsigned)s_res[0];
        state[S_K1]   = (s_res[0] < 0) ? 1u : (unsigned)s_res[1];
    }
}

// ---- post2: gated fallback hist2+select2 ----
__global__ __launch_bounds__(256, 8)
void post2(const uint4* __restrict__ x, long long n4,
           unsigned* __restrict__ fineB, unsigned* __restrict__ coarseB,
           unsigned* __restrict__ state)
{
    if (state[S_FLAG] == 0u) return;
    const int tid = threadIdx.x;
    unsigned pref = state[S_PREF];

    __shared__ unsigned hc[NCOARSE];
    for (int i = tid; i < NCOARSE; i += 256) hc[i] = 0u;
    __syncthreads();
    long long stride = (long long)gridDim.x * 256;
    for (long long i = (long long)blockIdx.x * 256 + tid; i < n4; i += stride) {
        uint4 v = x[i];
        unsigned u;
#define DO_C(c) u = v.c & 0x7FFFFFFFu;                                        \
        if ((u >> 19) == pref) {                                              \
            atomicAdd(&fineB[u & (NFINE - 1)], 1u);                           \
            atomicAdd(&hc[(u & (NFINE - 1)) >> 10], 1u); }
        DO_C(x) DO_C(y) DO_C(z) DO_C(w)
#undef DO_C
    }
    __syncthreads();
    for (int i = tid; i < NCOARSE; i += 256)
        if (hc[i]) atomicAdd(&coarseB[i], hc[i]);
    __syncthreads();

    __shared__ unsigned s_done;
    if (tid == 0) { __threadfence(); s_done = atomicAdd(&state[S_TICK3], 1u); }
    __syncthreads();
    if (s_done != gridDim.x - 1) return;
    __threadfence();

    __shared__ unsigned s_wsum[4];
    __shared__ int s_res[2];
    unsigned k1 = state[S_K1];
    select_desc_t<256>(coarseB, NCOARSE, k1, s_wsum, s_res);
    int c       = (s_res[0] < 0) ? 0 : s_res[0];
    unsigned k2 = (s_res[0] < 0) ? 1u : (unsigned)s_res[1];
    __syncthreads();
    select_desc_t<256>(fineB + (size_t)c * 1024, 1024, k2, s_wsum, s_res);
    int f = (s_res[0] < 0) ? 0 : s_res[0];
    if (tid == 0)
        state[S_T] = (pref << 19) | ((unsigned)c << 10) | (unsigned)f;
}

// ---- post3: gated fallback mask pass ----
__global__ __launch_bounds__(256)
void post3(const uint4* __restrict__ x, uint4* __restrict__ out, long long n4,
           const unsigned* __restrict__ state)
{
    if (state[S_FLAG] == 0u) return;
    unsigned t = state[S_T];
    long long stride = (long long)gridDim.x * 256;
    for (long long i = (long long)blockIdx.x * 256 + threadIdx.x; i < n4; i += stride) {
        uint4 v = x[i];
        uint4 r;
        r.x = ((v.x & 0x7FFFFFFFu) >= t) ? v.x : 0u;
        r.y = ((v.y & 0x7FFFFFFFu) >= t) ? v.y : 0u;
        r.z = ((v.z & 0x7FFFFFFFu) >= t) ? v.z : 0u;
        r.w = ((v.w & 0x7FFFFFFFu) >= t) ? v.w : 0u;
        out[i] = r;
    }
}

__global__ void seed_flag(unsigned* state)
{
    if (threadIdx.x == 0) state[S_FLAG] = 1u;
}

// ---------------- host ----------------
extern "C" void kernel_launch(void* const* d_in, const int* in_sizes, int n_in,
                              void* d_out, int out_size, void* d_ws, size_t ws_size,
                              hipStream_t stream)
{
    long long n = (long long)in_sizes[0];
    if (n <= 0) return;
    long long n4 = n >> 2;   // n = 4*4096*2048, divisible by 4

    const double FRACTION = 1.0 / 2.718281828459045;   // matches Python 1.0/math.e
    long long k = (long long)((double)n * FRACTION);
    if (k < 1) k = 1;

    auto al = [](size_t v) { return (v + 63) & ~(size_t)63; };

    // zeroed region: state | fineH | fineB | coarseB | histA  (~4.8 MB)
    const size_t off_fineH   = 64;
    const size_t off_fineB   = al(off_fineH + (size_t)NKEY * 4);
    const size_t off_coarseB = off_fineB   + (size_t)NFINE * 4;    // contiguous
    const size_t off_histA   = off_coarseB + (size_t)NCOARSE * 4;  // contiguous
    const size_t zero_end    = off_histA   + (size_t)NBIN1 * 4;
    // non-zeroed region (fully overwritten each iteration)
    const size_t off_coarseH = al(zero_end);
    const size_t off_tpart   = al(off_coarseH + (size_t)NCB * 4);
    const size_t off_wcnt    = al(off_tpart + (size_t)TPART * 8);
    const size_t off_bchi    = al(off_wcnt + (size_t)NWAVES * 4);
    const size_t off_cand    = al(off_bchi + (size_t)P_GRID * 4);
    const size_t need_fast   = off_cand + (size_t)NWAVES * CAPW * 8;   // ~26 MB
    const size_t need_fb     = zero_end;

    const uint4* x = (const uint4*)d_in[0];

    if (ws_size >= need_fast) {
        uint8_t* base = (uint8_t*)d_ws;
        unsigned* state   = (unsigned*)base;
        unsigned* fineH   = (unsigned*)(base + off_fineH);
        unsigned* fineB   = (unsigned*)(base + off_fineB);
        unsigned* coarseB = (unsigned*)(base + off_coarseB);
        unsigned* histA   = (unsigned*)(base + off_histA);
        unsigned* coarseH = (unsigned*)(base + off_coarseH);
        unsigned long long* tpart = (unsigned long long*)(base + off_tpart);
        unsigned* wavecnt = (unsigned*)(base + off_wcnt);
        unsigned* blkchi  = (unsigned*)(base + off_bchi);
        uint2*    cand    = (uint2*)   (base + off_cand);

        hipMemsetAsync(base, 0, zero_end, stream);
        pass_partition<<<P_GRID, P_BLK, 0, stream>>>(x, n4, (uint4*)d_out, cand,
                                                     wavecnt, blkchi, fineH, state);
        kcs  <<<KCS_GRID, 1024, 0, stream>>>(fineH, blkchi, wavecnt, coarseH,
                                             tpart, state, (unsigned)k);
        post1<<<1024, 256, 0, stream>>>(x, n4, n, (float*)d_out, cand, wavecnt,
                                        histA, state, (unsigned)k);
        post2<<<256, 256, 0, stream>>>(x, n4, fineB, coarseB, state);
        post3<<<1024, 256, 0, stream>>>(x, (uint4*)d_out, n4, state);
    } else {
        // tiny workspace: run the exact fallback chain unconditionally
        uint8_t* base;
        unsigned* state = (unsigned*)d_ws;       // 64 B state always in d_ws
        bool in_ws = (ws_size >= need_fb);
        base = in_ws ? (uint8_t*)d_ws : (uint8_t*)d_out;  // stage hists in d_out
        unsigned* fineB   = (unsigned*)(base + off_fineB);
        unsigned* coarseB = (unsigned*)(base + off_coarseB);
        unsigned* histA   = (unsigned*)(base + off_histA);

        if (in_ws) {
            hipMemsetAsync(base, 0, zero_end, stream);
        } else {
            hipMemsetAsync(state, 0, 64, stream);
            hipMemsetAsync(base + off_fineB, 0,
                           ((size_t)NFINE + NCOARSE + NBIN1) * 4, stream);
        }
        seed_flag<<<1, 64, 0, stream>>>(state);
        post1<<<1024, 256, 0, stream>>>(x, n4, n, (float*)d_out,
                                        (const uint2*)base, (const unsigned*)base,
                                        histA, state, (unsigned)k);
        post2<<<256, 256, 0, stream>>>(x, n4, fineB, coarseB, state);
        post3<<<1024, 256, 0, stream>>>(x, (uint4*)d_out, n4, state);
    }
}